// Round 14
// baseline (4709.822 us; speedup 1.0000x reference)
//
#include <hip/hip_runtime.h>
#include <hip/hip_fp16.h>
#include <math.h>

// ---------------------------------------------------------------------------
// RNN: h_{t+1} = relu(x_t @ W_in^T + h_t @ W_hh^T + b_hh + noise_t*scale)
// outputs: hidden_list [128,256,1024] f32, output_list [128,256,128] f32,
//          h_final [128,1024] f32 (concatenated flat in d_out)
//
// R14: ALL-REGISTER split-K dataflow RNN.
//  - R9 (762us) residual = LDS pipe (~3000cy/step: 248 ds_read_b128 + staging
//    + 2 barriers) + detection. R12 killed LDS but serialized 4 L2 RTs.
//    R13 flag-gate added a serial hop (944us). Fix both here:
//  - 256 blocks x 32 cols (8 groups x 32 slices), m=bx&7 XCD-striped
//    (R9-proven L2-local exchange), n=bx>>3.
//  - 4 waves = 4 K-quarters (256k each). Per wave: B-frags in REGISTERS
//    (2 col-tiles x 8 chunks x 8 halves = 64 VGPR, loaded once -- W is
//    time-invariant); A-quarter via ONE batched fragment-major sc0 load
//    (8KB contiguous, q[8]=32 VGPR live, R12 layout); 16 h-MFMAs + 2
//    x-MFMAs. No wtile, no htile, no staging ds_writes.
//  - Cross-wave split-K reduce via rtile[2][4][2][64] f32x4 (16KB LDS,
//    double-buffered by t&1) + ONE barrier/step. Waves 0,1 do reduce+
//    epilogue+publish (cols 0..15 / 16..31); waves 2,3 immediately spin
//    for t+1 (absorbs skew).
//  - Tag-in-data + sign trick (R10-proven): tag bit == fp16 sign bit,
//    relu(h)>=0 => fully-tagged tile = -h; validate uniformity, compensate
//    with sg=+/-1 at combine. Gen tag (t>>1)&1, 2-slot ring.
//  - Liveness: sc0 fast path; sleep(2) after 2 misses; sys-scope (sc0 sc1)
//    loads after 48 misses -> progress under ANY blockIdx->XCD mapping.
//  - WAR safety: block publishes h(t+1) only after the reduce barrier,
//    which requires all 4 waves to have consumed their quarter of h(t);
//    h(t+2) overwrites h(t) only after all blocks published h(t+1) ->
//    transitively all h(t) reads complete (R5-R12 inductive argument).
// ---------------------------------------------------------------------------

typedef _Float16 half8 __attribute__((ext_vector_type(8)));
typedef float    f32x4 __attribute__((ext_vector_type(4)));
typedef unsigned int u32x4 __attribute__((ext_vector_type(4)));
typedef unsigned long long u64;

#define SIGMA_F 0.05f

constexpr int T_  = 256;
constexpr int B_  = 128;
constexpr int NH  = 1024;
constexpr int NIN = 128;

// workspace layout (bytes)
constexpr size_t OFF_XT  = 0;                            // fp16 [T][B][NIN] 8.39MB
constexpr size_t OFF_NB  = (size_t)T_*B_*NIN*2;          // f32  [T][NH]     1.05MB
constexpr size_t OFF_WO  = OFF_NB + (size_t)T_*NH*4;     // fp16 [NIN][NH]   0.26MB
constexpr size_t OFF_HB  = OFF_WO + (size_t)NIN*NH*2;    // u32 [2][8][8192] 0.52MB

__device__ __forceinline__ unsigned short f16bits(float v) {
    return __half_as_ushort(__float2half(v));
}
__device__ __forceinline__ void ast(unsigned int* p, unsigned int v) {
    __hip_atomic_store(p, v, __ATOMIC_RELAXED, __HIP_MEMORY_SCOPE_AGENT);
}

// one K-quarter = 8 fragment-major dwordx4 loads (1KB apart), one vmcnt.
// p2 = p + 4096 (13-bit imm offset limit).
__device__ __forceinline__ void ld_chunk_sc0(u32x4 q[8], const char* p,
                                             const char* p2) {
    asm volatile(
        "global_load_dwordx4 %0, %8, off sc0\n\t"
        "global_load_dwordx4 %1, %8, off offset:1024 sc0\n\t"
        "global_load_dwordx4 %2, %8, off offset:2048 sc0\n\t"
        "global_load_dwordx4 %3, %8, off offset:3072 sc0\n\t"
        "global_load_dwordx4 %4, %9, off sc0\n\t"
        "global_load_dwordx4 %5, %9, off offset:1024 sc0\n\t"
        "global_load_dwordx4 %6, %9, off offset:2048 sc0\n\t"
        "global_load_dwordx4 %7, %9, off offset:3072 sc0\n\t"
        "s_waitcnt vmcnt(0)"
        : "=&v"(q[0]), "=&v"(q[1]), "=&v"(q[2]), "=&v"(q[3]),
          "=&v"(q[4]), "=&v"(q[5]), "=&v"(q[6]), "=&v"(q[7])
        : "v"(p), "v"(p2)
        : "memory");
}
__device__ __forceinline__ void ld_chunk_sys(u32x4 q[8], const char* p,
                                             const char* p2) {
    asm volatile(
        "global_load_dwordx4 %0, %8, off sc0 sc1\n\t"
        "global_load_dwordx4 %1, %8, off offset:1024 sc0 sc1\n\t"
        "global_load_dwordx4 %2, %8, off offset:2048 sc0 sc1\n\t"
        "global_load_dwordx4 %3, %8, off offset:3072 sc0 sc1\n\t"
        "global_load_dwordx4 %4, %9, off sc0 sc1\n\t"
        "global_load_dwordx4 %5, %9, off offset:1024 sc0 sc1\n\t"
        "global_load_dwordx4 %6, %9, off offset:2048 sc0 sc1\n\t"
        "global_load_dwordx4 %7, %9, off offset:3072 sc0 sc1\n\t"
        "s_waitcnt vmcnt(0)"
        : "=&v"(q[0]), "=&v"(q[1]), "=&v"(q[2]), "=&v"(q[3]),
          "=&v"(q[4]), "=&v"(q[5]), "=&v"(q[6]), "=&v"(q[7])
        : "v"(p), "v"(p2)
        : "memory");
}

// ---------------------------------------------------------------------------
__global__ void setup_kernel(const float* __restrict__ X,
                             const float* __restrict__ hidden,
                             const float* __restrict__ b_hh,
                             const float* __restrict__ W_out,
                             const float* __restrict__ alpha_w,
                             const float* __restrict__ noise,
                             unsigned short* __restrict__ Xt,
                             float* __restrict__ NB,
                             unsigned short* __restrict__ Wo,
                             unsigned int* __restrict__ Hb0,
                             unsigned int* __restrict__ Hb1)
{
    int idx = blockIdx.x * 256 + threadIdx.x;
    // X [B][T][NIN] -> Xt [T][B][NIN] fp16
    if (idx < B_ * T_ * NIN) {
        int d = idx & 127, rest = idx >> 7;
        int brow = rest & 127, t = rest >> 7;
        Xt[idx] = f16bits(X[((size_t)brow * T_ + t) * NIN + d]);
    }
    if (idx < T_ * NH) {
        int c = idx & (NH - 1);
        NB[idx] = b_hh[c] + noise[idx] * (sqrtf(2.0f / alpha_w[c]) * SIGMA_F);
    }
    if (idx < NIN * NH) Wo[idx] = f16bits(W_out[idx]);
    // Hf fragment-major: u32 idx -> (m, ki, lk, row, elem-pair)
    if (idx < B_ * NH / 2) {
        int m2   = idx >> 13;          // 8192 u32 per group
        int rest = idx & 8191;
        int kilk = rest >> 6;          // ki*4+lk in 0..127
        int r    = (rest >> 2) & 15;
        int ep   = rest & 3;
        int ki = kilk >> 2, lkq = kilk & 3;
        int col  = ki * 32 + lkq * 8 + ep * 2;
        int brow = m2 * 16 + r;
        unsigned int lo = f16bits(hidden[(size_t)brow * NH + col]);
        unsigned int hi = f16bits(hidden[(size_t)brow * NH + col + 1]);
        Hb0[idx] = (lo | (hi << 16)) & 0x7FFF7FFFu;  // gen-0 tag (0)
        Hb1[idx] = 0x80008000u;                      // poison (tag 1)
    }
}

// ---------------------------------------------------------------------------
// Persistent RNN: 256 blocks x 256 threads (1 block/CU, all CUs).
// Roles: m = bx&7 (batch group, XCD-striped), n = bx>>3 in [0,32) (32 cols).
// Wave kq = K-quarter. Waves 0,1 additionally own epilogue col-tiles 0,1.
__global__ __launch_bounds__(256, 1) void rnn_step_kernel(
    const float* __restrict__ W_hh, const float* __restrict__ W_in,
    const unsigned short* __restrict__ Xt, const float* __restrict__ NB,
    unsigned int* __restrict__ Hb0, unsigned int* __restrict__ Hb1,
    float* __restrict__ hidden_list, float* __restrict__ h_final)
{
    __shared__ f32x4 rtile[2][4][2][64];   // [t&1][kq][ntile][lane] = 16KB

    const int tid = threadIdx.x;
    const int m = blockIdx.x & 7;    // batch group (XCD-striped)
    const int n = blockIdx.x >> 3;   // column slice [0,32)

    const int kq = tid >> 6;         // wave = K-quarter
    const int lane = tid & 63;
    const int l15 = lane & 15, lk = lane >> 4;

    // ---- per-lane register B-fragments (loaded once; W time-invariant) ----
    auto cvt8 = [](const float* s) {
        half8 h;
        #pragma unroll
        for (int j = 0; j < 8; ++j) h[j] = (_Float16)s[j];
        return h;
    };
    half8 bh[2][8];   // [col-tile][chunk-within-quarter]
    half8 bx2[2];
    #pragma unroll
    for (int j = 0; j < 2; ++j) {
        const int col = n * 32 + j * 16 + l15;
        #pragma unroll
        for (int c = 0; c < 8; ++c)
            bh[j][c] = cvt8(W_hh + (size_t)col * NH + (kq * 8 + c) * 32 + lk * 8);
        bx2[j] = cvt8(W_in + (size_t)col * NIN + kq * 32 + lk * 8);
    }

    // consumer: wave kq's quarter, fragment-major (bytes)
    const size_t consOff = (size_t)m * 32768 + (size_t)kq * 8192
                         + lk * 256 + l15 * 16;
    // producer (waves 0,1): col gcolp, rows lk*4+r2
    const int gcolp = n * 32 + kq * 16 + l15;     // valid for kq<2
    const size_t pubOff = (size_t)m * 32768
                        + (((gcolp >> 5) * 4 + ((gcolp >> 3) & 3)) << 8)
                        + lk * 64 + (gcolp & 7) * 2;

    for (int t = 0; t < T_; ++t) {
        const int par = t & 1;
        const bool tagset = ((t >> 1) & 1) != 0;
        const unsigned int e32 = tagset ? 0x80008000u : 0u;

        // ---- x-part first (independent of exchange) ----
        half8 xv = *(const half8*)(Xt + ((size_t)t * B_ + m * 16 + l15) * NIN
                                   + kq * 32 + lk * 8);
        f32x4 ax0 = {0.f, 0.f, 0.f, 0.f}, ax1 = {0.f, 0.f, 0.f, 0.f};
        ax0 = __builtin_amdgcn_mfma_f32_16x16x32_f16(xv, bx2[0], ax0, 0, 0, 0);
        ax1 = __builtin_amdgcn_mfma_f32_16x16x32_f16(xv, bx2[1], ax1, 0, 0, 0);

        // ---- spin on THIS wave's K-quarter (one batched RT per round) ----
        const char* pc = (const char*)(par ? Hb1 : Hb0) + consOff;
        u32x4 q[8];
        {
            int esc = 0;
            ld_chunk_sc0(q, pc, pc + 4096);
            for (;;) {
                u32x4 e4 = {e32, e32, e32, e32};
                u32x4 red4 = q[0] ^ e4;
                #pragma unroll
                for (int j = 1; j < 8; ++j) red4 |= q[j] ^ e4;
                unsigned int red = red4[0] | red4[1] | red4[2] | red4[3];
                if (!(red & 0x80008000u)) break;
                ++esc;
                if (esc >= 2)  __builtin_amdgcn_s_sleep(2);
                if (esc < 48) ld_chunk_sc0(q, pc, pc + 4096);
                else          ld_chunk_sys(q, pc, pc + 4096);  // liveness
            }
        }

        // ---- 16 h-MFMAs straight from registers (sign-tagged A) ----
        f32x4 ah0 = {0.f, 0.f, 0.f, 0.f}, ah1 = {0.f, 0.f, 0.f, 0.f};
        #pragma unroll
        for (int c = 0; c < 8; ++c) {
            half8 av = __builtin_bit_cast(half8, q[c]);
            ah0 = __builtin_amdgcn_mfma_f32_16x16x32_f16(av, bh[0][c], ah0, 0, 0, 0);
            ah1 = __builtin_amdgcn_mfma_f32_16x16x32_f16(av, bh[1][c], ah1, 0, 0, 0);
        }

        // ---- combine with sign compensation, write partials ----
        const float sg = tagset ? -1.f : 1.f;
        f32x4 p0, p1;
        #pragma unroll
        for (int r2 = 0; r2 < 4; ++r2) {
            p0[r2] = fmaf(sg, ah0[r2], ax0[r2]);
            p1[r2] = fmaf(sg, ah1[r2], ax1[r2]);
        }
        rtile[par][kq][0][lane] = p0;
        rtile[par][kq][1][lane] = p1;

        __syncthreads();   // the ONE barrier: partials visible; double-buffer
                           // rtile[par] handles WAR across steps.

        // ---- epilogue: waves 0,1 reduce + publish; waves 2,3 go to t+1 ----
        if (kq < 2) {
            f32x4 s = rtile[par][0][kq][lane];
            #pragma unroll
            for (int k2 = 1; k2 < 4; ++k2) {
                f32x4 v = rtile[par][k2][kq][lane];
                #pragma unroll
                for (int r2 = 0; r2 < 4; ++r2) s[r2] += v[r2];
            }
            const float nb = NB[t * NH + gcolp];
            float hv[4];
            #pragma unroll
            for (int r2 = 0; r2 < 4; ++r2) {
                float v = s[r2] + nb;
                hv[r2] = v > 0.f ? v : 0.f;
            }

            // publish h_{t+1} FIRST (tag in-word, fragment-major slot)
            if (t < T_ - 1) {
                unsigned int* hn = par ? Hb0 : Hb1;
                const unsigned int tagb = (((t + 1) >> 1) & 1) ? 0x80008000u : 0u;
                #pragma unroll
                for (int r2 = 0; r2 < 4; ++r2) {
                    float other = __shfl_xor(hv[r2], 1);
                    if (!(lane & 1)) {
                        unsigned int val = (unsigned int)f16bits(hv[r2]) |
                                           ((unsigned int)f16bits(other) << 16) | tagb;
                        ast((unsigned int*)((char*)hn + pubOff + r2 * 16), val);
                    }
                }
            }

            // fp32 outputs
            #pragma unroll
            for (int r2 = 0; r2 < 4; ++r2) {
                int brow = m * 16 + lk * 4 + r2;
                hidden_list[((size_t)brow * T_ + t) * NH + gcolp] = hv[r2];
            }
            if (t == T_ - 1) {
                #pragma unroll
                for (int r2 = 0; r2 < 4; ++r2) {
                    int brow = m * 16 + lk * 4 + r2;
                    h_final[(size_t)brow * NH + gcolp] = hv[r2];
                }
            }
        }
    }
}

// ---------------------------------------------------------------------------
// Readout: Y[32768,128] = HL[32768,1024](f32->f16) @ Wo^T(f16), fp32 out.
__global__ __launch_bounds__(256, 4) void ygemm_kernel(
    const float* __restrict__ HL, const unsigned short* __restrict__ Wo,
    float* __restrict__ Y)
{
    typedef unsigned short ushort8 __attribute__((ext_vector_type(8)));
    const int tid = threadIdx.x;
    const int wave = tid >> 6, lane = tid & 63;
    const int l15 = lane & 15, lk = lane >> 4;
    const size_t rowbase = (size_t)blockIdx.x * 64;

    f32x4 acc[4][2] = {};

    #pragma unroll 2
    for (int ki = 0; ki < 32; ++ki) {
        const int k0 = ki * 32 + lk * 8;
        half8 bfr[2];
        #pragma unroll
        for (int nt = 0; nt < 2; ++nt) {
            int ncol = (wave * 2 + nt) * 16 + l15;
            ushort8 braw = *(const ushort8*)(Wo + ncol * NH + k0);
            bfr[nt] = __builtin_bit_cast(half8, braw);
        }
        #pragma unroll
        for (int mt = 0; mt < 4; ++mt) {
            size_t row = rowbase + mt * 16 + l15;
            const float4* ap = (const float4*)(HL + row * NH + k0);
            float4 a0 = ap[0];
            float4 a1 = ap[1];
            half8 a = { (_Float16)a0.x, (_Float16)a0.y, (_Float16)a0.z, (_Float16)a0.w,
                        (_Float16)a1.x, (_Float16)a1.y, (_Float16)a1.z, (_Float16)a1.w };
            #pragma unroll
            for (int nt = 0; nt < 2; ++nt)
                acc[mt][nt] = __builtin_amdgcn_mfma_f32_16x16x32_f16(a, bfr[nt], acc[mt][nt], 0, 0, 0);
        }
    }

    #pragma unroll
    for (int mt = 0; mt < 4; ++mt) {
        #pragma unroll
        for (int nt = 0; nt < 2; ++nt) {
            int ncol = (wave * 2 + nt) * 16 + l15;
            #pragma unroll
            for (int r = 0; r < 4; ++r) {
                size_t row = rowbase + mt * 16 + lk * 4 + r;
                Y[row * NIN + ncol] = acc[mt][nt][r];
            }
        }
    }
}

// ---------------------------------------------------------------------------
extern "C" void kernel_launch(void* const* d_in, const int* in_sizes, int n_in,
                              void* d_out, int out_size, void* d_ws, size_t ws_size,
                              hipStream_t stream)
{
    const float* X      = (const float*)d_in[0];
    const float* hidden = (const float*)d_in[1];
    const float* W_in   = (const float*)d_in[2];
    const float* W_hh   = (const float*)d_in[3];
    const float* b_hh   = (const float*)d_in[4];
    const float* W_out  = (const float*)d_in[5];
    const float* alpha  = (const float*)d_in[6];
    const float* noise  = (const float*)d_in[7];

    char* ws = (char*)d_ws;   // ~10.2 MB
    unsigned short* Xt = (unsigned short*)(ws + OFF_XT);
    float*          NB = (float*)(ws + OFF_NB);
    unsigned short* Wo = (unsigned short*)(ws + OFF_WO);
    unsigned int*  Hb0 = (unsigned int*)(ws + OFF_HB);
    unsigned int*  Hb1 = Hb0 + (size_t)B_ * NH / 2;

    float* hidden_list = (float*)d_out;                                  // [128,256,1024]
    float* output_list = hidden_list + (size_t)B_ * T_ * NH;             // [128,256,128]
    float* h_final     = output_list + (size_t)B_ * T_ * NIN;            // [128,1024]

    setup_kernel<<<(B_ * T_ * NIN + 255) / 256, 256, 0, stream>>>(
        X, hidden, b_hh, W_out, alpha, noise, Xt, NB, Wo, Hb0, Hb1);

    rnn_step_kernel<<<256, 256, 0, stream>>>(
        W_hh, W_in, Xt, NB, Hb0, Hb1, hidden_list, h_final);

    ygemm_kernel<<<(B_ * T_) / 64, 256, 0, stream>>>(
        hidden_list, Wo, output_list);
}